// Round 1
// baseline (314.175 us; speedup 1.0000x reference)
//
#include <hip/hip_runtime.h>
#include <cstdint>

// ---------------------------------------------------------------------------
// minerva_transform: logits = (Xn @ Dn^T)^3 @ rh ; preds = sigmoid(logits)
//   Xn = l2norm(X@g_w.T+g_b) [4096,512] bf16, Dn likewise [20000,512] bf16
//   rh = (2r-1)*h_w + h_b  [20000] fp32
// All heavy GEMMs in bf16 MFMA 16x16x32, m97-style 128x128 tiles with
// global_load_lds width-16 staging. sign(s)|s|^3 == s^3 (odd power).
// ---------------------------------------------------------------------------

typedef __attribute__((ext_vector_type(4))) float  f32x4;
typedef __attribute__((ext_vector_type(8))) __bf16 bf16x8;
typedef __attribute__((ext_vector_type(4))) __bf16 bf16x4;

#define AS1CAST(p) ((__attribute__((address_space(1))) unsigned int*)(uintptr_t)(p))
#define AS3CAST(p) ((__attribute__((address_space(3))) unsigned int*)(uintptr_t)(p))

__device__ __forceinline__ void gload_lds16(const void* g, void* l) {
  // 16B per lane, LDS dest = wave-uniform base + lane*16 (we pass exactly that)
  __builtin_amdgcn_global_load_lds(AS1CAST(g), AS3CAST(l), 16, 0, 0);
}

// ------------------------- elementwise helpers -----------------------------

__global__ void k_f32_to_bf16(const float* __restrict__ in, __bf16* __restrict__ out, int n) {
  int i = (blockIdx.x * blockDim.x + threadIdx.x) * 4;
  if (i + 4 <= n) {
    float4 v = *(const float4*)(in + i);
    bf16x4 o;
    o[0] = (__bf16)v.x; o[1] = (__bf16)v.y; o[2] = (__bf16)v.z; o[3] = (__bf16)v.w;
    *(bf16x4*)(out + i) = o;
  }
}

__global__ void k_rh(const float* __restrict__ r, const float* __restrict__ hw,
                     const float* __restrict__ hb, float* __restrict__ rh, int n) {
  int i = blockIdx.x * blockDim.x + threadIdx.x;
  if (i < n) rh[i] = (2.0f * r[i] - 1.0f) * hw[0] + hb[0];
}

__global__ void k_zero_f32(float* __restrict__ p, int n) {
  int i = blockIdx.x * blockDim.x + threadIdx.x;
  if (i < n) p[i] = 0.0f;
}

__global__ void k_finalize(const float* __restrict__ logits, float* __restrict__ out, int n) {
  int i = blockIdx.x * blockDim.x + threadIdx.x;
  if (i < n) {
    float L = logits[i];
    out[i] = L;
    out[n + i] = 1.0f / (1.0f + expf(-L));
  }
}

// ------------------------- embedding GEMM ----------------------------------
// C[m,e] = sum_k A[m,k]*G[e,k] + bias[e]
// A: [M,768] bf16 row-major, G: [512,768] bf16 row-major, C: [M,512] fp32.
// Tile 128x128, BK=32, 256 threads (4 waves, each 64x64 = 4x4 frags).

__global__ __launch_bounds__(256, 2)
void k_embed_gemm(const __bf16* __restrict__ A, const __bf16* __restrict__ G,
                  const float* __restrict__ bias, float* __restrict__ C, int M) {
  constexpr int K = 768;
  constexpr int E = 512;
  __shared__ __bf16 As[128 * 32];
  __shared__ __bf16 Bs[128 * 32];
  const int tid  = threadIdx.x;
  const int wave = tid >> 6;
  const int lane = tid & 63;
  const int m0 = blockIdx.y * 128;
  const int n0 = blockIdx.x * 128;
  const int r_in = lane >> 2;          // row within 16-row chunk
  const int kp   = (lane & 3) * 8;     // k offset within 32-wide slice

  int ar0 = m0 + wave * 16 + r_in;        if (ar0 >= M) ar0 = M - 1;
  int ar1 = m0 + (wave + 4) * 16 + r_in;  if (ar1 >= M) ar1 = M - 1;
  const int br0 = n0 + wave * 16 + r_in;        // always < 512
  const int br1 = n0 + (wave + 4) * 16 + r_in;

  const __bf16* ga0 = A + (size_t)ar0 * K + kp;
  const __bf16* ga1 = A + (size_t)ar1 * K + kp;
  const __bf16* gb0 = G + (size_t)br0 * K + kp;
  const __bf16* gb1 = G + (size_t)br1 * K + kp;
  __bf16* la0 = &As[(size_t)wave * 512 + (size_t)lane * 8];
  __bf16* la1 = &As[(size_t)(wave + 4) * 512 + (size_t)lane * 8];
  __bf16* lb0 = &Bs[(size_t)wave * 512 + (size_t)lane * 8];
  __bf16* lb1 = &Bs[(size_t)(wave + 4) * 512 + (size_t)lane * 8];

  const int mw = (wave & 1) * 64;
  const int nw = (wave >> 1) * 64;
  const int quad = lane >> 4;
  const int l15  = lane & 15;

  f32x4 acc[4][4] = {};

  for (int kb = 0; kb < K; kb += 32) {
    gload_lds16(ga0 + kb, la0);
    gload_lds16(ga1 + kb, la1);
    gload_lds16(gb0 + kb, lb0);
    gload_lds16(gb1 + kb, lb1);
    __syncthreads();   // waits vmcnt(0) per wave -> tiles resident
    bf16x8 af[4], bfr[4];
#pragma unroll
    for (int i = 0; i < 4; ++i)
      af[i] = *(const bf16x8*)&As[(mw + i * 16 + l15) * 32 + quad * 8];
#pragma unroll
    for (int j = 0; j < 4; ++j)
      bfr[j] = *(const bf16x8*)&Bs[(nw + j * 16 + l15) * 32 + quad * 8];
#pragma unroll
    for (int i = 0; i < 4; ++i)
#pragma unroll
      for (int j = 0; j < 4; ++j)
        acc[i][j] = __builtin_amdgcn_mfma_f32_16x16x32_bf16(af[i], bfr[j], acc[i][j], 0, 0, 0);
    __syncthreads();   // protect LDS before next staging
  }

  // epilogue: C[row][col] = acc + bias[col]; C/D frag: col=lane&15, row=quad*4+reg
#pragma unroll
  for (int j = 0; j < 4; ++j) {
    const int col = n0 + nw + j * 16 + l15;
    const float bv = bias[col];
#pragma unroll
    for (int i = 0; i < 4; ++i) {
      const int row = m0 + mw + i * 16 + quad * 4;
#pragma unroll
      for (int rr = 0; rr < 4; ++rr) {
        if (row + rr < M)
          C[(size_t)(row + rr) * E + col] = acc[i][j][rr] + bv;
      }
    }
  }
}

// ------------------------- row L2-normalize --------------------------------
// one wave per row of 512 fp32 -> bf16

__global__ void k_normalize(const float* __restrict__ Xe, __bf16* __restrict__ Xn, int M) {
  const int row  = blockIdx.x * 4 + (threadIdx.x >> 6);
  const int lane = threadIdx.x & 63;
  if (row >= M) return;
  const float4* p = (const float4*)(Xe + (size_t)row * 512);
  float4 v0 = p[lane];
  float4 v1 = p[lane + 64];
  float s = v0.x * v0.x + v0.y * v0.y + v0.z * v0.z + v0.w * v0.w
          + v1.x * v1.x + v1.y * v1.y + v1.z * v1.z + v1.w * v1.w;
#pragma unroll
  for (int off = 32; off > 0; off >>= 1) s += __shfl_xor(s, off);
  const float sc = 1.0f / fmaxf(sqrtf(s), 1e-12f);
  bf16x4 o0, o1;
  o0[0] = (__bf16)(v0.x * sc); o0[1] = (__bf16)(v0.y * sc);
  o0[2] = (__bf16)(v0.z * sc); o0[3] = (__bf16)(v0.w * sc);
  o1[0] = (__bf16)(v1.x * sc); o1[1] = (__bf16)(v1.y * sc);
  o1[2] = (__bf16)(v1.z * sc); o1[3] = (__bf16)(v1.w * sc);
  bf16x4* q = (bf16x4*)(Xn + (size_t)row * 512);
  q[lane]      = o0;
  q[lane + 64] = o1;
}

// ------------------------- fused Minerva GEMM ------------------------------
// For M-tile 128 x N-tile 128: s = Xn@Dn^T (K=512), then
// logits[m] += sum_n s^3 * rh[n].  Per-block LDS row accumulator, then one
// global atomicAdd per row.

__global__ __launch_bounds__(256, 2)
void k_minerva(const __bf16* __restrict__ Xn, const __bf16* __restrict__ Dn,
               const float* __restrict__ rh, float* __restrict__ logits, int N) {
  constexpr int K = 512;
  __shared__ __bf16 As[128 * 32];
  __shared__ __bf16 Bs[128 * 32];
  __shared__ float lsum[128];
  const int tid  = threadIdx.x;
  const int wave = tid >> 6;
  const int lane = tid & 63;
  const int m0 = blockIdx.y * 128;   // 32 M-tiles (4096)
  const int n0 = blockIdx.x * 128;   // 157 N-tiles (20000 -> pad)
  if (tid < 128) lsum[tid] = 0.0f;

  const int r_in = lane >> 2;
  const int kp   = (lane & 3) * 8;

  const int ar0 = m0 + wave * 16 + r_in;         // always < 4096
  const int ar1 = m0 + (wave + 4) * 16 + r_in;
  int br0 = n0 + wave * 16 + r_in;        if (br0 >= N) br0 = N - 1;
  int br1 = n0 + (wave + 4) * 16 + r_in;  if (br1 >= N) br1 = N - 1;

  const __bf16* ga0 = Xn + (size_t)ar0 * K + kp;
  const __bf16* ga1 = Xn + (size_t)ar1 * K + kp;
  const __bf16* gb0 = Dn + (size_t)br0 * K + kp;
  const __bf16* gb1 = Dn + (size_t)br1 * K + kp;
  __bf16* la0 = &As[(size_t)wave * 512 + (size_t)lane * 8];
  __bf16* la1 = &As[(size_t)(wave + 4) * 512 + (size_t)lane * 8];
  __bf16* lb0 = &Bs[(size_t)wave * 512 + (size_t)lane * 8];
  __bf16* lb1 = &Bs[(size_t)(wave + 4) * 512 + (size_t)lane * 8];

  const int mw = (wave & 1) * 64;
  const int nw = (wave >> 1) * 64;
  const int quad = lane >> 4;
  const int l15  = lane & 15;

  f32x4 acc[4][4] = {};

  for (int kb = 0; kb < K; kb += 32) {
    gload_lds16(ga0 + kb, la0);
    gload_lds16(ga1 + kb, la1);
    gload_lds16(gb0 + kb, lb0);
    gload_lds16(gb1 + kb, lb1);
    __syncthreads();
    bf16x8 af[4], bfr[4];
#pragma unroll
    for (int i = 0; i < 4; ++i)
      af[i] = *(const bf16x8*)&As[(mw + i * 16 + l15) * 32 + quad * 8];
#pragma unroll
    for (int j = 0; j < 4; ++j)
      bfr[j] = *(const bf16x8*)&Bs[(nw + j * 16 + l15) * 32 + quad * 8];
#pragma unroll
    for (int i = 0; i < 4; ++i)
#pragma unroll
      for (int j = 0; j < 4; ++j)
        acc[i][j] = __builtin_amdgcn_mfma_f32_16x16x32_bf16(af[i], bfr[j], acc[i][j], 0, 0, 0);
    __syncthreads();
  }

  // epilogue: s^3 * rh, reduce over the 16 lanes sharing the same rows
  float rhv[4];
#pragma unroll
  for (int j = 0; j < 4; ++j) {
    const int col = n0 + nw + j * 16 + l15;
    rhv[j] = (col < N) ? rh[col] : 0.0f;   // zero kills padded/clamped cols
  }
#pragma unroll
  for (int i = 0; i < 4; ++i) {
    float part[4] = {0.0f, 0.0f, 0.0f, 0.0f};
#pragma unroll
    for (int j = 0; j < 4; ++j)
#pragma unroll
      for (int rr = 0; rr < 4; ++rr) {
        const float s = acc[i][j][rr];
        part[rr] += s * s * s * rhv[j];
      }
#pragma unroll
    for (int rr = 0; rr < 4; ++rr) {
      float v = part[rr];
      v += __shfl_xor(v, 1);
      v += __shfl_xor(v, 2);
      v += __shfl_xor(v, 4);
      v += __shfl_xor(v, 8);
      if (l15 == 0) atomicAdd(&lsum[mw + i * 16 + quad * 4 + rr], v);
    }
  }
  __syncthreads();
  if (tid < 128) atomicAdd(&logits[m0 + tid], lsum[tid]);
}

// ------------------------- launcher ----------------------------------------

extern "C" void kernel_launch(void* const* d_in, const int* in_sizes, int n_in,
                              void* d_out, int out_size, void* d_ws, size_t ws_size,
                              hipStream_t stream) {
  constexpr int B = 4096, N = 20000, F = 768, E = 512;

  const float* X   = (const float*)d_in[0];
  const float* D   = (const float*)d_in[1];
  const float* r   = (const float*)d_in[2];
  const float* g_w = (const float*)d_in[3];
  const float* g_b = (const float*)d_in[4];
  const float* h_w = (const float*)d_in[5];
  const float* h_b = (const float*)d_in[6];
  float* out = (float*)d_out;

  // ws layout (bytes), all 256-aligned by construction; total ~106.7 MiB
  char* ws = (char*)d_ws;
  __bf16* Xb  = (__bf16*)(ws + 0);               // 4096*768*2   = 6,291,456
  __bf16* Db  = (__bf16*)(ws + 6291456);         // 20000*768*2  = 30,720,000
  __bf16* Gb  = (__bf16*)(ws + 37011456);        // 512*768*2    = 786,432
  float*  Xe  = (float*) (ws + 37797888);        // 4096*512*4   = 8,388,608
  float*  De  = (float*) (ws + 46186496);        // 20000*512*4  = 40,960,000
  __bf16* Xn  = (__bf16*)(ws + 87146496);        // 4096*512*2   = 4,194,304
  __bf16* Dn  = (__bf16*)(ws + 91340800);        // 20000*512*2  = 20,480,000
  float*  rh  = (float*) (ws + 111820800);       // 20000*4      = 80,000
  float*  lg  = (float*) (ws + 111900800);       // 4096*4       = 16,384

  // 1. fp32 -> bf16 conversions
  k_f32_to_bf16<<<(B * F / 4 + 255) / 256, 256, 0, stream>>>(X, Xb, B * F);
  k_f32_to_bf16<<<(N * F / 4 + 255) / 256, 256, 0, stream>>>(D, Db, N * F);
  k_f32_to_bf16<<<(E * F / 4 + 255) / 256, 256, 0, stream>>>(g_w, Gb, E * F);
  k_rh<<<(N + 255) / 256, 256, 0, stream>>>(r, h_w, h_b, rh, N);

  // 2. embedding GEMMs (+bias), fp32 out
  k_embed_gemm<<<dim3(E / 128, B / 128), 256, 0, stream>>>(Xb, Gb, g_b, Xe, B);
  k_embed_gemm<<<dim3(E / 128, (N + 127) / 128), 256, 0, stream>>>(Db, Gb, g_b, De, N);

  // 3. L2 normalize -> bf16
  k_normalize<<<B / 4, 256, 0, stream>>>(Xe, Xn, B);
  k_normalize<<<N / 4, 256, 0, stream>>>(De, Dn, N);

  // 4. fused cosine^3-weighted retrieval
  k_zero_f32<<<(B + 255) / 256, 256, 0, stream>>>(lg, B);
  k_minerva<<<dim3((N + 127) / 128, B / 128), 256, 0, stream>>>(Xn, Dn, rh, lg, N);

  // 5. logits + sigmoid
  k_finalize<<<(B + 255) / 256, 256, 0, stream>>>(lg, out, B);
}

// Round 2
// 258.720 us; speedup vs baseline: 1.2143x; 1.2143x over previous
//
#include <hip/hip_runtime.h>
#include <cstdint>

// ---------------------------------------------------------------------------
// minerva_transform: logits = (Xn @ Dn^T)^3 @ rh ; preds = sigmoid(logits)
// R2: panel-swizzled fused GEMM (L2 locality), BK=64 + XOR-swizzled LDS
// (bank-conflict-free b128 reads), aux kernels fused 10 -> 5 launches,
// embed GEMM writes bf16 + row-norm^2 atomics (no fp32 round-trip).
// ---------------------------------------------------------------------------

typedef __attribute__((ext_vector_type(4))) float  f32x4;
typedef __attribute__((ext_vector_type(8))) __bf16 bf16x8;
typedef __attribute__((ext_vector_type(4))) __bf16 bf16x4;

constexpr int B = 4096, N = 20000, F = 768, E = 512;

#define AS1CAST(p) ((__attribute__((address_space(1))) unsigned int*)(uintptr_t)(p))
#define AS3CAST(p) ((__attribute__((address_space(3))) unsigned int*)(uintptr_t)(p))

__device__ __forceinline__ void gload_lds16(const void* g, void* l) {
  // 16B/lane, LDS dest = wave-uniform base + lane*16 (layout guarantees this)
  __builtin_amdgcn_global_load_lds(AS1CAST(g), AS3CAST(l), 16, 0, 0);
}

// ------------------------- fused prep --------------------------------------
// converts X, D, g_w to bf16; rh = (2r-1)*h_w + h_b; zeroes logits + norm2

__global__ void k_prep(const float* __restrict__ X, const float* __restrict__ D,
                       const float* __restrict__ G, const float* __restrict__ r,
                       const float* __restrict__ hw, const float* __restrict__ hb,
                       __bf16* __restrict__ Xb, __bf16* __restrict__ Db,
                       __bf16* __restrict__ Gb, float* __restrict__ rh,
                       float* __restrict__ lg, float* __restrict__ norm2) {
  const int t = blockIdx.x * blockDim.x + threadIdx.x;
  const int stride = gridDim.x * blockDim.x;
  constexpr int nX = B * F / 4, nD = N * F / 4, nG = E * F / 4;
  constexpr int tot = nX + nD + nG;
  for (int i = t; i < tot; i += stride) {
    const float4* src; bf16x4* dst; int off;
    if (i < nX)           { src = (const float4*)X; dst = (bf16x4*)Xb; off = i; }
    else if (i < nX + nD) { src = (const float4*)D; dst = (bf16x4*)Db; off = i - nX; }
    else                  { src = (const float4*)G; dst = (bf16x4*)Gb; off = i - nX - nD; }
    float4 v = src[off];
    bf16x4 o;
    o[0] = (__bf16)v.x; o[1] = (__bf16)v.y; o[2] = (__bf16)v.z; o[3] = (__bf16)v.w;
    dst[off] = o;
  }
  if (t < N) rh[t] = (2.0f * r[t] - 1.0f) * hw[0] + hb[0];
  if (t < B) lg[t] = 0.0f;
  if (t < B + N) norm2[t] = 0.0f;
}

// ------------------------- combined embedding GEMM -------------------------
// rows 0..31 tiles = X, 32..188 = D.  C[g,e] = sum_k A[m,k]*G[e,k] + bias[e]
// writes bf16 Eb[24096,512] and accumulates per-row sum-of-squares (of the
// bf16-rounded values) into norm2 via atomics.

__global__ __launch_bounds__(256, 2)
void k_embed(const __bf16* __restrict__ Xb, const __bf16* __restrict__ Db,
             const __bf16* __restrict__ Gb, const float* __restrict__ bias,
             __bf16* __restrict__ Eb, float* __restrict__ norm2) {
  constexpr int K = F;  // 768
  __shared__ __bf16 As[128 * 32];
  __shared__ __bf16 Bs[128 * 32];
  __shared__ float ssum[128];
  const int tid  = threadIdx.x;
  const int wave = tid >> 6;
  const int lane = tid & 63;
  const int by = blockIdx.y;
  const bool isX = (by < B / 128);
  const __bf16* A = isX ? Xb : Db;
  const int m0 = isX ? by * 128 : (by - B / 128) * 128;
  const int Mr = isX ? B : N;
  const int g0 = by * 128;              // row offset into Eb / norm2
  const int n0 = blockIdx.x * 128;      // e-dim tile
  if (tid < 128) ssum[tid] = 0.0f;

  const int r_in = lane >> 2;
  const int kp   = (lane & 3) * 8;
  int ar0 = m0 + wave * 16 + r_in;        if (ar0 >= Mr) ar0 = Mr - 1;
  int ar1 = m0 + (wave + 4) * 16 + r_in;  if (ar1 >= Mr) ar1 = Mr - 1;
  const int br0 = n0 + wave * 16 + r_in;        // < 512
  const int br1 = n0 + (wave + 4) * 16 + r_in;

  const __bf16* ga0 = A + (size_t)ar0 * K + kp;
  const __bf16* ga1 = A + (size_t)ar1 * K + kp;
  const __bf16* gb0 = Gb + (size_t)br0 * K + kp;
  const __bf16* gb1 = Gb + (size_t)br1 * K + kp;
  __bf16* la0 = &As[(size_t)wave * 512 + (size_t)lane * 8];
  __bf16* la1 = &As[(size_t)(wave + 4) * 512 + (size_t)lane * 8];
  __bf16* lb0 = &Bs[(size_t)wave * 512 + (size_t)lane * 8];
  __bf16* lb1 = &Bs[(size_t)(wave + 4) * 512 + (size_t)lane * 8];

  const int mw = (wave & 1) * 64;
  const int nw = (wave >> 1) * 64;
  const int quad = lane >> 4;
  const int l15  = lane & 15;

  f32x4 acc[4][4] = {};

  for (int kb = 0; kb < K; kb += 32) {
    gload_lds16(ga0 + kb, la0);
    gload_lds16(ga1 + kb, la1);
    gload_lds16(gb0 + kb, lb0);
    gload_lds16(gb1 + kb, lb1);
    __syncthreads();
    bf16x8 af[4], bfr[4];
#pragma unroll
    for (int i = 0; i < 4; ++i)
      af[i] = *(const bf16x8*)&As[(mw + i * 16 + l15) * 32 + quad * 8];
#pragma unroll
    for (int j = 0; j < 4; ++j)
      bfr[j] = *(const bf16x8*)&Bs[(nw + j * 16 + l15) * 32 + quad * 8];
#pragma unroll
    for (int i = 0; i < 4; ++i)
#pragma unroll
      for (int j = 0; j < 4; ++j)
        acc[i][j] = __builtin_amdgcn_mfma_f32_16x16x32_bf16(af[i], bfr[j], acc[i][j], 0, 0, 0);
    __syncthreads();
  }

  // epilogue: bf16 store + row sum-of-squares.  C/D frag: col=l15, row=quad*4+reg
#pragma unroll
  for (int i = 0; i < 4; ++i) {
    float part[4] = {0.0f, 0.0f, 0.0f, 0.0f};
#pragma unroll
    for (int j = 0; j < 4; ++j) {
      const int col = n0 + nw + j * 16 + l15;
      const float bv = bias[col];
#pragma unroll
      for (int rr = 0; rr < 4; ++rr) {
        const int row = mw + i * 16 + quad * 4 + rr;   // tile-local
        if (m0 + row < Mr) {
          const __bf16 hv = (__bf16)(acc[i][j][rr] + bv);
          Eb[(size_t)(g0 + row) * E + col] = hv;
          const float vb = (float)hv;
          part[rr] += vb * vb;
        }
      }
    }
#pragma unroll
    for (int rr = 0; rr < 4; ++rr) {
      float v = part[rr];
      v += __shfl_xor(v, 1);
      v += __shfl_xor(v, 2);
      v += __shfl_xor(v, 4);
      v += __shfl_xor(v, 8);
      if (l15 == 0) atomicAdd(&ssum[mw + i * 16 + quad * 4 + rr], v);
    }
  }
  __syncthreads();
  if (tid < 128 && m0 + tid < Mr) atomicAdd(&norm2[g0 + tid], ssum[tid]);
}

// ------------------------- normalize (bf16 -> bf16) ------------------------

__global__ void k_normall(const __bf16* __restrict__ Eb, const float* __restrict__ norm2,
                          __bf16* __restrict__ Nb, int rows) {
  const int row  = blockIdx.x * 4 + (threadIdx.x >> 6);
  const int lane = threadIdx.x & 63;
  if (row >= rows) return;
  bf16x8 v = ((const bf16x8*)(Eb + (size_t)row * E))[lane];
  const float sc = 1.0f / fmaxf(sqrtf(norm2[row]), 1e-12f);
  bf16x8 o;
#pragma unroll
  for (int k = 0; k < 8; ++k) o[k] = (__bf16)((float)v[k] * sc);
  ((bf16x8*)(Nb + (size_t)row * E))[lane] = o;
}

// ------------------------- fused Minerva GEMM ------------------------------
// s = Xn@Dn^T (K=512) on a 128x128 tile; logits[m] += sum_n s^3 * rh[n].
// Panel-swizzled 1-D grid (n-fast panels of W n-tiles) for L2 locality.
// BK=64, XOR-swizzled LDS: LDS[row][c] holds global colgrp c^(row&7) --
// staging DMA still writes base+lane*16; reads hit all 8 bank groups evenly.

__global__ __launch_bounds__(256, 2)
void k_minerva(const __bf16* __restrict__ Xn, const __bf16* __restrict__ Dn,
               const float* __restrict__ rh, float* __restrict__ logits) {
  constexpr int K  = 512;
  constexpr int MT = B / 128;          // 32
  constexpr int NT = (N + 127) / 128;  // 157
  constexpr int W  = 20;               // panel width (n-tiles)
  __shared__ __bf16 As[128 * 64];
  __shared__ __bf16 Bs[128 * 64];
  __shared__ float lsum[128];
  const int tid  = threadIdx.x;
  const int lane = tid & 63;
  const int wave = tid >> 6;

  // panel swizzle: 7 panels of 20x32 + final 17x32 (total 5024 blocks)
  const int bid   = blockIdx.x;
  const int panel = bid / (W * MT);
  const int bn    = panel * W;
  const int Wp    = min(W, NT - bn);
  const int rem   = bid - panel * (W * MT);
  const int mt    = rem / Wp;
  const int nt    = bn + rem % Wp;
  const int m0 = mt * 128, n0 = nt * 128;
  if (tid < 128) lsum[tid] = 0.0f;

  // staging: thread t -> row=(t>>3)+q*32, fetches global colgrp (t&7)^(row&7)
  const int srow = tid >> 3;
  const int scg  = (tid & 7) ^ (srow & 7);
  const __bf16* ga[4];
  const __bf16* gb[4];
  __bf16* la[4];
  __bf16* lb[4];
#pragma unroll
  for (int q = 0; q < 4; ++q) {
    const int row = srow + q * 32;
    const int arow = m0 + row;                       // < 4096 always
    int brow = n0 + row; if (brow >= N) brow = N - 1;
    ga[q] = Xn + (size_t)arow * K + scg * 8;
    gb[q] = Dn + (size_t)brow * K + scg * 8;
    la[q] = &As[q * 2048 + tid * 8];                 // = wave*1024B + q*4096B + lane*16B
    lb[q] = &Bs[q * 2048 + tid * 8];
  }

  const int mw = (wave & 1) * 64;
  const int nw = (wave >> 1) * 64;
  const int quad = lane >> 4;
  const int l15  = lane & 15;
  f32x4 acc[4][4] = {};

  for (int kb = 0; kb < K; kb += 64) {
#pragma unroll
    for (int q = 0; q < 4; ++q) gload_lds16(ga[q] + kb, la[q]);
#pragma unroll
    for (int q = 0; q < 4; ++q) gload_lds16(gb[q] + kb, lb[q]);
    __syncthreads();
#pragma unroll
    for (int h = 0; h < 2; ++h) {
      bf16x8 af[4], bfr[4];
#pragma unroll
      for (int i = 0; i < 4; ++i) {
        const int r = mw + i * 16 + l15;
        af[i] = *(const bf16x8*)&As[r * 64 + ((quad + h * 4) ^ (r & 7)) * 8];
      }
#pragma unroll
      for (int j = 0; j < 4; ++j) {
        const int r = nw + j * 16 + l15;
        bfr[j] = *(const bf16x8*)&Bs[r * 64 + ((quad + h * 4) ^ (r & 7)) * 8];
      }
#pragma unroll
      for (int i = 0; i < 4; ++i)
#pragma unroll
        for (int j = 0; j < 4; ++j)
          acc[i][j] = __builtin_amdgcn_mfma_f32_16x16x32_bf16(af[i], bfr[j], acc[i][j], 0, 0, 0);
    }
    __syncthreads();
  }

  // epilogue: s^3 * rh, 16-lane reduce, LDS row accumulator, 1 atomic/row
  float rhv[4];
#pragma unroll
  for (int j = 0; j < 4; ++j) {
    const int col = n0 + nw + j * 16 + l15;
    rhv[j] = (col < N) ? rh[col] : 0.0f;   // zero kills padded/clamped cols
  }
#pragma unroll
  for (int i = 0; i < 4; ++i) {
    float part[4] = {0.0f, 0.0f, 0.0f, 0.0f};
#pragma unroll
    for (int j = 0; j < 4; ++j)
#pragma unroll
      for (int rr = 0; rr < 4; ++rr) {
        const float s = acc[i][j][rr];
        part[rr] += s * s * s * rhv[j];
      }
#pragma unroll
    for (int rr = 0; rr < 4; ++rr) {
      float v = part[rr];
      v += __shfl_xor(v, 1);
      v += __shfl_xor(v, 2);
      v += __shfl_xor(v, 4);
      v += __shfl_xor(v, 8);
      if (l15 == 0) atomicAdd(&lsum[mw + i * 16 + quad * 4 + rr], v);
    }
  }
  __syncthreads();
  if (tid < 128) atomicAdd(&logits[m0 + tid], lsum[tid]);
}

// ------------------------- finalize ----------------------------------------

__global__ void k_finalize(const float* __restrict__ logits, float* __restrict__ out, int n) {
  int i = blockIdx.x * blockDim.x + threadIdx.x;
  if (i < n) {
    float L = logits[i];
    out[i] = L;
    out[n + i] = 1.0f / (1.0f + expf(-L));
  }
}

// ------------------------- launcher ----------------------------------------

extern "C" void kernel_launch(void* const* d_in, const int* in_sizes, int n_in,
                              void* d_out, int out_size, void* d_ws, size_t ws_size,
                              hipStream_t stream) {
  const float* X   = (const float*)d_in[0];
  const float* D   = (const float*)d_in[1];
  const float* r   = (const float*)d_in[2];
  const float* g_w = (const float*)d_in[3];
  const float* g_b = (const float*)d_in[4];
  const float* h_w = (const float*)d_in[5];
  const float* h_b = (const float*)d_in[6];
  float* out = (float*)d_out;

  // ws layout (bytes), 256-aligned, total ~87.3 MB
  char* ws = (char*)d_ws;
  __bf16* Xb    = (__bf16*)(ws + 0);             // 4096*768*2   = 6,291,456
  __bf16* Db    = (__bf16*)(ws + 6291456);       // 20000*768*2  = 30,720,000
  __bf16* Gb    = (__bf16*)(ws + 37011456);      // 512*768*2    = 786,432
  __bf16* Eb    = (__bf16*)(ws + 37797888);      // 24096*512*2  = 24,674,304
  __bf16* Nb    = (__bf16*)(ws + 62472192);      // 24096*512*2  = 24,674,304
  float*  rh    = (float*) (ws + 87146496);      // 20000*4      = 80,000
  float*  norm2 = (float*) (ws + 87226496);      // 24096*4      = 96,384
  float*  lg    = (float*) (ws + 87322880);      // 4096*4       = 16,384

  // 1. fused convert + rh + zero (grid-stride)
  k_prep<<<2048, 256, 0, stream>>>(X, D, g_w, r, h_w, h_b, Xb, Db, Gb, rh, lg, norm2);

  // 2. combined embedding GEMM (X rows then D rows), bf16 out + norm2 atomics
  k_embed<<<dim3(E / 128, B / 128 + (N + 127) / 128), 256, 0, stream>>>(
      Xb, Db, Gb, g_b, Eb, norm2);

  // 3. normalize all 24096 rows
  k_normall<<<(B + N + 3) / 4, 256, 0, stream>>>(Eb, norm2, Nb, B + N);

  // 4. fused cosine^3-weighted retrieval (panel-swizzled)
  k_minerva<<<7 * 20 * 32 + 17 * 32, 256, 0, stream>>>(Nb, Nb + (size_t)B * E, rh, lg);

  // 5. logits + sigmoid
  k_finalize<<<(B + 255) / 256, 256, 0, stream>>>(lg, out, B);
}

// Round 3
// 257.530 us; speedup vs baseline: 1.2200x; 1.0046x over previous
//
#include <hip/hip_runtime.h>
#include <cstdint>

// ---------------------------------------------------------------------------
// minerva_transform: logits = (l2(Xe) @ l2(De)^T)^3 @ rh ; preds = sigmoid
// R3: occupancy 2->3 blocks/CU (launch_bounds waves/EU=3), normalize folded
// into minerva epilogue (s^3 rh = acc^3 * ix^3 * (id^3 rh)), embed GEMM gets
// BK=64 + XOR-swizzled LDS, m-fast panel ordering for per-XCD L2 fit.
// ---------------------------------------------------------------------------

typedef __attribute__((ext_vector_type(4))) float  f32x4;
typedef __attribute__((ext_vector_type(8))) __bf16 bf16x8;
typedef __attribute__((ext_vector_type(4))) __bf16 bf16x4;

constexpr int B = 4096, N = 20000, F = 768, E = 512;

#define AS1CAST(p) ((__attribute__((address_space(1))) unsigned int*)(uintptr_t)(p))
#define AS3CAST(p) ((__attribute__((address_space(3))) unsigned int*)(uintptr_t)(p))

__device__ __forceinline__ void gload_lds16(const void* g, void* l) {
  // 16B/lane, LDS dest = wave-uniform base + lane*16 (layout guarantees this)
  __builtin_amdgcn_global_load_lds(AS1CAST(g), AS3CAST(l), 16, 0, 0);
}

// ------------------------- fused prep --------------------------------------

__global__ void k_prep(const float* __restrict__ X, const float* __restrict__ D,
                       const float* __restrict__ G, const float* __restrict__ r,
                       const float* __restrict__ hw, const float* __restrict__ hb,
                       __bf16* __restrict__ Xb, __bf16* __restrict__ Db,
                       __bf16* __restrict__ Gb, float* __restrict__ rh,
                       float* __restrict__ lg, float* __restrict__ norm2) {
  const int t = blockIdx.x * blockDim.x + threadIdx.x;
  const int stride = gridDim.x * blockDim.x;
  constexpr int nX = B * F / 4, nD = N * F / 4, nG = E * F / 4;
  constexpr int tot = nX + nD + nG;
  for (int i = t; i < tot; i += stride) {
    const float4* src; bf16x4* dst; int off;
    if (i < nX)           { src = (const float4*)X; dst = (bf16x4*)Xb; off = i; }
    else if (i < nX + nD) { src = (const float4*)D; dst = (bf16x4*)Db; off = i - nX; }
    else                  { src = (const float4*)G; dst = (bf16x4*)Gb; off = i - nX - nD; }
    float4 v = src[off];
    bf16x4 o;
    o[0] = (__bf16)v.x; o[1] = (__bf16)v.y; o[2] = (__bf16)v.z; o[3] = (__bf16)v.w;
    dst[off] = o;
  }
  if (t < N) rh[t] = (2.0f * r[t] - 1.0f) * hw[0] + hb[0];
  if (t < B) lg[t] = 0.0f;
  if (t < B + N) norm2[t] = 0.0f;
}

// ------------------------- combined embedding GEMM -------------------------
// row-tiles 0..31 = X, 32..188 = D.  Eb[g,e] = bf16(sum_k A[m,k]G[e,k]+b[e]),
// norm2[g] += sum_e Eb[g,e]^2.  BK=64, XOR-swizzled LDS (conflict-free).

__global__ __launch_bounds__(256, 3)
void k_embed(const __bf16* __restrict__ Xb, const __bf16* __restrict__ Db,
             const __bf16* __restrict__ Gb, const float* __restrict__ bias,
             __bf16* __restrict__ Eb, float* __restrict__ norm2) {
  constexpr int K = F;  // 768
  __shared__ __bf16 As[128 * 64];
  __shared__ __bf16 Bs[128 * 64];
  __shared__ float ssum[128];
  const int tid  = threadIdx.x;
  const int wave = tid >> 6;
  const int lane = tid & 63;
  const int by = blockIdx.y;
  const bool isX = (by < B / 128);
  const __bf16* A = isX ? Xb : Db;
  const int m0 = isX ? by * 128 : (by - B / 128) * 128;
  const int Mr = isX ? B : N;
  const int g0 = by * 128;              // row offset into Eb / norm2
  const int n0 = blockIdx.x * 128;      // e-dim tile
  if (tid < 128) ssum[tid] = 0.0f;

  // staging: thread t -> row=(t>>3)+q*32, global colgrp (t&7)^(row&7)
  const int srow = tid >> 3;
  const int scg  = (tid & 7) ^ (srow & 7);
  const __bf16* ga[4];
  const __bf16* gb[4];
  __bf16* la[4];
  __bf16* lb[4];
#pragma unroll
  for (int q = 0; q < 4; ++q) {
    const int row = srow + q * 32;
    int arow = m0 + row; if (arow >= Mr) arow = Mr - 1;
    const int brow = n0 + row;                       // < 512 always
    ga[q] = A  + (size_t)arow * K + scg * 8;
    gb[q] = Gb + (size_t)brow * K + scg * 8;
    la[q] = &As[q * 2048 + tid * 8];
    lb[q] = &Bs[q * 2048 + tid * 8];
  }

  const int mw = (wave & 1) * 64;
  const int nw = (wave >> 1) * 64;
  const int quad = lane >> 4;
  const int l15  = lane & 15;
  f32x4 acc[4][4] = {};

  for (int kb = 0; kb < K; kb += 64) {
#pragma unroll
    for (int q = 0; q < 4; ++q) gload_lds16(ga[q] + kb, la[q]);
#pragma unroll
    for (int q = 0; q < 4; ++q) gload_lds16(gb[q] + kb, lb[q]);
    __syncthreads();
#pragma unroll
    for (int h = 0; h < 2; ++h) {
      bf16x8 af[4], bfr[4];
#pragma unroll
      for (int i = 0; i < 4; ++i) {
        const int rr = mw + i * 16 + l15;
        af[i] = *(const bf16x8*)&As[rr * 64 + ((quad + h * 4) ^ (rr & 7)) * 8];
      }
#pragma unroll
      for (int j = 0; j < 4; ++j) {
        const int rr = nw + j * 16 + l15;
        bfr[j] = *(const bf16x8*)&Bs[rr * 64 + ((quad + h * 4) ^ (rr & 7)) * 8];
      }
#pragma unroll
      for (int i = 0; i < 4; ++i)
#pragma unroll
        for (int j = 0; j < 4; ++j)
          acc[i][j] = __builtin_amdgcn_mfma_f32_16x16x32_bf16(af[i], bfr[j], acc[i][j], 0, 0, 0);
    }
    __syncthreads();
  }

  // epilogue: bf16 store + row sum-of-squares.  C/D: col=l15, row=quad*4+reg
#pragma unroll
  for (int i = 0; i < 4; ++i) {
    float part[4] = {0.0f, 0.0f, 0.0f, 0.0f};
#pragma unroll
    for (int j = 0; j < 4; ++j) {
      const int col = n0 + nw + j * 16 + l15;
      const float bv = bias[col];
#pragma unroll
      for (int rr = 0; rr < 4; ++rr) {
        const int row = mw + i * 16 + quad * 4 + rr;   // tile-local
        if (m0 + row < Mr) {
          const __bf16 hv = (__bf16)(acc[i][j][rr] + bv);
          Eb[(size_t)(g0 + row) * E + col] = hv;
          const float vb = (float)hv;
          part[rr] += vb * vb;
        }
      }
    }
#pragma unroll
    for (int rr = 0; rr < 4; ++rr) {
      float v = part[rr];
      v += __shfl_xor(v, 1);
      v += __shfl_xor(v, 2);
      v += __shfl_xor(v, 4);
      v += __shfl_xor(v, 8);
      if (l15 == 0) atomicAdd(&ssum[mw + i * 16 + quad * 4 + rr], v);
    }
  }
  __syncthreads();
  if (tid < 128 && m0 + tid < Mr) atomicAdd(&norm2[g0 + tid], ssum[tid]);
}

// ------------------------- fused Minerva GEMM ------------------------------
// acc = Xe@De^T (unnormalized, K=512); epilogue uses
//   s^3*rh = acc^3 * ix^3 * (id^3*rh),  ix^3 hoisted out of the j-loop.
// m-fast panel ordering: consecutive blocks share the n-progression so each
// XCD's L2 holds a small Xn slice + the Dn panel.

__global__ __launch_bounds__(256, 3)
void k_minerva(const __bf16* __restrict__ Xe, const __bf16* __restrict__ De,
               const float* __restrict__ norm2, const float* __restrict__ rh,
               float* __restrict__ logits) {
  constexpr int K  = 512;
  constexpr int MT = B / 128;          // 32
  constexpr int NT = (N + 127) / 128;  // 157
  constexpr int W  = 20;               // panel width (n-tiles)
  __shared__ __bf16 As[128 * 64];
  __shared__ __bf16 Bs[128 * 64];
  __shared__ float lsum[128];
  const int tid  = threadIdx.x;
  const int lane = tid & 63;
  const int wave = tid >> 6;

  // panel decomposition, m-fast within panel
  const int bid   = blockIdx.x;
  const int panel = bid / (W * MT);
  const int bn    = panel * W;
  const int rem   = bid - panel * (W * MT);
  const int mt    = rem % MT;
  const int nt    = bn + rem / MT;
  const int m0 = mt * 128, n0 = nt * 128;
  if (tid < 128) lsum[tid] = 0.0f;

  const int srow = tid >> 3;
  const int scg  = (tid & 7) ^ (srow & 7);
  const __bf16* ga[4];
  const __bf16* gb[4];
  __bf16* la[4];
  __bf16* lb[4];
#pragma unroll
  for (int q = 0; q < 4; ++q) {
    const int row = srow + q * 32;
    const int arow = m0 + row;                       // < 4096 always
    int brow = n0 + row; if (brow >= N) brow = N - 1;
    ga[q] = Xe + (size_t)arow * K + scg * 8;
    gb[q] = De + (size_t)brow * K + scg * 8;
    la[q] = &As[q * 2048 + tid * 8];
    lb[q] = &Bs[q * 2048 + tid * 8];
  }

  const int mw = (wave & 1) * 64;
  const int nw = (wave >> 1) * 64;
  const int quad = lane >> 4;
  const int l15  = lane & 15;
  f32x4 acc[4][4] = {};

  for (int kb = 0; kb < K; kb += 64) {
#pragma unroll
    for (int q = 0; q < 4; ++q) gload_lds16(ga[q] + kb, la[q]);
#pragma unroll
    for (int q = 0; q < 4; ++q) gload_lds16(gb[q] + kb, lb[q]);
    __syncthreads();
#pragma unroll
    for (int h = 0; h < 2; ++h) {
      bf16x8 af[4], bfr[4];
#pragma unroll
      for (int i = 0; i < 4; ++i) {
        const int rr = mw + i * 16 + l15;
        af[i] = *(const bf16x8*)&As[rr * 64 + ((quad + h * 4) ^ (rr & 7)) * 8];
      }
#pragma unroll
      for (int j = 0; j < 4; ++j) {
        const int rr = nw + j * 16 + l15;
        bfr[j] = *(const bf16x8*)&Bs[rr * 64 + ((quad + h * 4) ^ (rr & 7)) * 8];
      }
#pragma unroll
      for (int i = 0; i < 4; ++i)
#pragma unroll
        for (int j = 0; j < 4; ++j)
          acc[i][j] = __builtin_amdgcn_mfma_f32_16x16x32_bf16(af[i], bfr[j], acc[i][j], 0, 0, 0);
    }
    __syncthreads();
  }

  // ---- epilogue ----
  float id3rh[4];
#pragma unroll
  for (int j = 0; j < 4; ++j) {
    const int col = n0 + nw + j * 16 + l15;
    if (col < N) {
      const float id = 1.0f / fmaxf(sqrtf(norm2[B + col]), 1e-12f);
      id3rh[j] = id * id * id * rh[col];
    } else id3rh[j] = 0.0f;   // kills padded/clamped cols
  }
#pragma unroll
  for (int i = 0; i < 4; ++i) {
    float ix3[4];
#pragma unroll
    for (int rr = 0; rr < 4; ++rr) {
      const int row = m0 + mw + i * 16 + quad * 4 + rr;   // < 4096
      const float ix = 1.0f / fmaxf(sqrtf(norm2[row]), 1e-12f);
      ix3[rr] = ix * ix * ix;
    }
    float part[4] = {0.0f, 0.0f, 0.0f, 0.0f};
#pragma unroll
    for (int j = 0; j < 4; ++j)
#pragma unroll
      for (int rr = 0; rr < 4; ++rr) {
        const float a = acc[i][j][rr];
        const float a2 = a * a;
        part[rr] = fmaf(a2 * a, id3rh[j], part[rr]);
      }
#pragma unroll
    for (int rr = 0; rr < 4; ++rr) {
      float v = part[rr] * ix3[rr];
      v += __shfl_xor(v, 1);
      v += __shfl_xor(v, 2);
      v += __shfl_xor(v, 4);
      v += __shfl_xor(v, 8);
      if (l15 == 0) atomicAdd(&lsum[mw + i * 16 + quad * 4 + rr], v);
    }
  }
  __syncthreads();
  if (tid < 128) atomicAdd(&logits[m0 + tid], lsum[tid]);
}

// ------------------------- finalize ----------------------------------------

__global__ void k_finalize(const float* __restrict__ logits, float* __restrict__ out, int n) {
  int i = blockIdx.x * blockDim.x + threadIdx.x;
  if (i < n) {
    float L = logits[i];
    out[i] = L;
    out[n + i] = 1.0f / (1.0f + expf(-L));
  }
}

// ------------------------- launcher ----------------------------------------

extern "C" void kernel_launch(void* const* d_in, const int* in_sizes, int n_in,
                              void* d_out, int out_size, void* d_ws, size_t ws_size,
                              hipStream_t stream) {
  const float* X   = (const float*)d_in[0];
  const float* D   = (const float*)d_in[1];
  const float* r   = (const float*)d_in[2];
  const float* g_w = (const float*)d_in[3];
  const float* g_b = (const float*)d_in[4];
  const float* h_w = (const float*)d_in[5];
  const float* h_b = (const float*)d_in[6];
  float* out = (float*)d_out;

  // ws layout (bytes), 256-aligned, total ~62.7 MB
  char* ws = (char*)d_ws;
  __bf16* Xb    = (__bf16*)(ws + 0);             // 4096*768*2   = 6,291,456
  __bf16* Db    = (__bf16*)(ws + 6291456);       // 20000*768*2  = 30,720,000
  __bf16* Gb    = (__bf16*)(ws + 37011456);      // 512*768*2    = 786,432
  __bf16* Eb    = (__bf16*)(ws + 37797888);      // 24096*512*2  = 24,674,304
  float*  rh    = (float*) (ws + 62472192);      // 20000*4      = 80,000
  float*  norm2 = (float*) (ws + 62552192);      // 24096*4      = 96,384
  float*  lg    = (float*) (ws + 62648576);      // 4096*4       = 16,384

  // 1. fused convert + rh + zero
  k_prep<<<2048, 256, 0, stream>>>(X, D, g_w, r, h_w, h_b, Xb, Db, Gb, rh, lg, norm2);

  // 2. combined embedding GEMM, bf16 out + norm2 atomics
  k_embed<<<dim3(E / 128, B / 128 + (N + 127) / 128), 256, 0, stream>>>(
      Xb, Db, Gb, g_b, Eb, norm2);

  // 3. fused cosine^3-weighted retrieval (normalization folded into epilogue)
  k_minerva<<<157 * 32, 256, 0, stream>>>(Eb, Eb + (size_t)B * E, norm2, rh, lg);

  // 4. logits + sigmoid
  k_finalize<<<(B + 255) / 256, 256, 0, stream>>>(lg, out, B);
}